// Round 17
// baseline (277.604 us; speedup 1.0000x reference)
//
#include <hip/hip_runtime.h>
#include <hip/hip_bf16.h>

typedef unsigned short u16;
typedef unsigned char u8;
typedef unsigned long long u64;
typedef __bf16 bf16x8 __attribute__((ext_vector_type(8)));
typedef float f32x4 __attribute__((ext_vector_type(4)));

#define AS1 __attribute__((address_space(1)))
#define AS3 __attribute__((address_space(3)))
#define GLL16(gp, lp) __builtin_amdgcn_global_load_lds((AS1 const unsigned int*)(gp), (AS3 unsigned int*)(lp), 16, 0, 0)
#define NTL4(p) __builtin_nontemporal_load((const f32x4*)(p))

__device__ __forceinline__ u16 f2bf(float f) {
    unsigned u = __builtin_bit_cast(unsigned, f);
    unsigned r = u + 0x7FFFu + ((u >> 16) & 1u);
    return (u16)(r >> 16);
}

// ---------------- prep: f32->bf16 cast of Q/K/V (blocks 0..1023) + weight transpose (1024..2047) ----------------
__global__ __launch_bounds__(256) void prep_kernel(
    const float* __restrict__ q, const float* __restrict__ k, const float* __restrict__ v,
    u16* __restrict__ xq, u16* __restrict__ xk, u16* __restrict__ xv,
    const float* __restrict__ W0, const float* __restrict__ W1,
    const float* __restrict__ W2, const float* __restrict__ W3,
    u16* __restrict__ T0, u16* __restrict__ T1, u16* __restrict__ T2, u16* __restrict__ T3) {
    const int gb = blockIdx.x, tid = threadIdx.x;
    if (gb < 1024) {
        const int n4 = 4 * 1024 * 1024 / 4;
        const int stride = 1024 * 256;
        for (int i = gb * 256 + tid; i < n4; i += stride) {
            float4 a = ((const float4*)q)[i];
            float4 b = ((const float4*)k)[i];
            float4 c = ((const float4*)v)[i];
            ((ushort4*)xq)[i] = make_ushort4(f2bf(a.x), f2bf(a.y), f2bf(a.z), f2bf(a.w));
            ((ushort4*)xk)[i] = make_ushort4(f2bf(b.x), f2bf(b.y), f2bf(b.z), f2bf(b.w));
            ((ushort4*)xv)[i] = make_ushort4(f2bf(c.x), f2bf(c.y), f2bf(c.z), f2bf(c.w));
        }
    } else {
        __shared__ float t[64][65];
        const int idx = gb - 1024;
        const int bz = idx >> 8, by = (idx >> 4) & 15, bx = idx & 15;
        const float* W = (bz == 0) ? W0 : (bz == 1) ? W1 : (bz == 2) ? W2 : W3;
        u16* T = (bz == 0) ? T0 : (bz == 1) ? T1 : (bz == 2) ? T2 : T3;
        const int n0 = bx * 64, k0 = by * 64;
        const int tx = tid & 63, ty = tid >> 6;
        for (int j = ty; j < 64; j += 4) t[j][tx] = W[(size_t)(k0 + j) * 1024 + n0 + tx];
        __syncthreads();
        for (int j = ty; j < 64; j += 4) T[(size_t)(n0 + j) * 1024 + k0 + tx] = f2bf(t[tx][j]);
    }
}

// ---------------- mask -> packed bitmask body (self-detecting dtype); runs as qkv z==3 ----------------
#define MN_LOOP(PRED)                                                     \
    for (int row = wave; row < 65536; row += nw) {                        \
        size_t base = (size_t)row * 1024;                                 \
        u64 myw = 0;                                                      \
        _Pragma("unroll")                                                 \
        for (int kb = 0; kb < 16; ++kb) {                                 \
            size_t gi = base + kb * 64 + lane;                            \
            bool p = (PRED);                                              \
            u64 w = __ballot(p);                                          \
            if (lane == kb) myw = w;                                      \
        }                                                                 \
        if (lane < 16) MB[(size_t)row * 16 + lane] = myw;                 \
    }

__device__ __forceinline__ void masknorm_body(const void* __restrict__ mp,
                                              u64* __restrict__ MB,
                                              int* sh, int tid, int wave, int nw) {
    if (tid == 0) { sh[0] = 0; sh[1] = 0; }
    __syncthreads();
    {
        const u8* m8 = (const u8*)mp;
        int c1 = 0, bg = 0;
        for (int i = tid; i < 16384; i += 256) {
            u8 vv = m8[i];
            if (vv) {
                if ((i & 3) == 1) c1++;
                if (vv > 1) bg++;
            }
        }
        atomicAdd(&sh[0], c1);
        atomicAdd(&sh[1], bg);
    }
    __syncthreads();
    const int flag = (sh[1] == 0) ? (sh[0] ? 0 : 1) : (sh[0] ? 3 : 2);
    const int lane = tid & 63;
    if (flag == 0) {
        const u8* m8 = (const u8*)mp;
        MN_LOOP(m8[gi] != 0)
    } else if (flag == 1) {
        const int* m32 = (const int*)mp;
        MN_LOOP(m32[gi] != 0)
    } else if (flag == 2) {
        const unsigned* mf = (const unsigned*)mp;
        MN_LOOP((mf[gi] << 1) != 0)
    } else {
        const u16* mb = (const u16*)mp;
        MN_LOOP((mb[gi] & 0x7FFF) != 0)
    }
}

// ================= GEMM core v2 (round 10, unchanged) =================
__device__ __forceinline__ void gemm_core(const u16* __restrict__ A, const u16* __restrict__ Bt,
                                          u16* sA, u16* sB, f32x4 (&acc)[4][4],
                                          int tid, int bm, int bn) {
    const int lane = tid & 63, wid = tid >> 6;
    const int wr = wid >> 1, wc = wid & 1;
    const int l15 = lane & 15, l4 = lane >> 4;
    const int srow = tid >> 2, sslot = tid & 3;
    const int soff = (sslot ^ ((srow >> 1) & 3)) * 8;
    const u16* aSrc = A + (size_t)(bm * 128 + srow) * 1024 + soff;
    const u16* bSrc = Bt + (size_t)(bn * 128 + srow) * 1024 + soff;
    u16* const dA0 = sA + wid * 512;
    u16* const dA1 = sA + 2048 + wid * 512;
    u16* const dB0 = sB + wid * 512;
    u16* const dB1 = sB + 2048 + wid * 512;

#define GSTAGE(BUF, T)                                                  \
    do {                                                                \
        GLL16(aSrc + (T) * 32, dA0 + (BUF) * 4096);                     \
        GLL16(aSrc + 65536 + (T) * 32, dA1 + (BUF) * 4096);             \
        GLL16(bSrc + (T) * 32, dB0 + (BUF) * 4096);                     \
        GLL16(bSrc + 65536 + (T) * 32, dB1 + (BUF) * 4096);             \
    } while (0)

#define GCOMPUTE(BUF)                                                             \
    do {                                                                          \
        bf16x8 af[4], bfv[4];                                                     \
        _Pragma("unroll")                                                         \
        for (int m = 0; m < 4; ++m) {                                             \
            const int rr = wr * 64 + m * 16 + l15;                                \
            af[m] = *(const bf16x8*)(sA + (BUF) * 4096 + rr * 32 +                \
                                     ((l4 ^ ((rr >> 1) & 3)) * 8));               \
        }                                                                         \
        _Pragma("unroll")                                                         \
        for (int n = 0; n < 4; ++n) {                                             \
            const int rr = wc * 64 + n * 16 + l15;                                \
            bfv[n] = *(const bf16x8*)(sB + (BUF) * 4096 + rr * 32 +               \
                                      ((l4 ^ ((rr >> 1) & 3)) * 8));              \
        }                                                                         \
        _Pragma("unroll")                                                         \
        for (int m = 0; m < 4; ++m)                                               \
            _Pragma("unroll")                                                     \
            for (int n = 0; n < 4; ++n)                                           \
                acc[m][n] = __builtin_amdgcn_mfma_f32_16x16x32_bf16(af[m], bfv[n], acc[m][n], 0, 0, 0); \
    } while (0)

#define GBODY(T, BUF, NBUF, WSTR)                                       \
    do {                                                                \
        if ((T) + 2 < 32) {                                             \
            GSTAGE(NBUF, (T) + 2);                                      \
            __builtin_amdgcn_sched_barrier(0);                          \
        }                                                               \
        GCOMPUTE(BUF);                                                  \
        if ((T) + 1 < 32) {                                             \
            asm volatile(WSTR ::: "memory");                            \
            __builtin_amdgcn_sched_barrier(0);                          \
            __builtin_amdgcn_s_barrier();                               \
            __builtin_amdgcn_sched_barrier(0);                          \
        }                                                               \
    } while (0)

    GSTAGE(0, 0);
    GSTAGE(1, 1);
    __builtin_amdgcn_sched_barrier(0);
    asm volatile("s_waitcnt vmcnt(4)" ::: "memory");
    __builtin_amdgcn_sched_barrier(0);
    __builtin_amdgcn_s_barrier();
    __builtin_amdgcn_sched_barrier(0);

    for (int it = 0; it < 10; ++it) {
        const int t0 = it * 3;
        GBODY(t0 + 0, 0, 2, "s_waitcnt vmcnt(4)");
        GBODY(t0 + 1, 1, 0, "s_waitcnt vmcnt(4)");
        GBODY(t0 + 2, 2, 1, "s_waitcnt vmcnt(4)");
    }
    GBODY(30, 0, 2, "s_waitcnt vmcnt(0)");
    GBODY(31, 1, 0, "s_waitcnt vmcnt(0)");
#undef GBODY
#undef GCOMPUTE
#undef GSTAGE
}

// ---------------- merged QKV GEMM + masknorm (z==3): XCD-locality remap ----------------
__global__ __launch_bounds__(256, 3) void qkv_gemm(
    const u16* __restrict__ XQ, const u16* __restrict__ XK, const u16* __restrict__ XV,
    const u16* __restrict__ WQT, const u16* __restrict__ WKT, const u16* __restrict__ WVT,
    const float* __restrict__ bq, const float* __restrict__ bk, const float* __restrict__ bv,
    u16* __restrict__ QS, u16* __restrict__ KS, u16* __restrict__ VT,
    const void* __restrict__ maskp, u64* __restrict__ MBw) {
    __shared__ __align__(16) u16 smem[24576];
    const int z = blockIdx.z;
    const int tid = threadIdx.x;
    if (z == 3) {
        const int wave = (blockIdx.y * 8 + blockIdx.x) * 4 + (tid >> 6);
        masknorm_body(maskp, MBw, (int*)smem, tid, wave, 1024);
        return;
    }
    const u16* A  = (z == 0) ? XQ : (z == 1) ? XK : XV;
    const u16* Bt = (z == 0) ? WQT : (z == 1) ? WKT : WVT;
    const float* bias = (z == 0) ? bq : (z == 1) ? bk : bv;
    const int lane = tid & 63, wid = tid >> 6;
    const int bm = blockIdx.x * 4 + (blockIdx.y >> 3);
    const int bn = blockIdx.y & 7;
    const int wr = wid >> 1, wc = wid & 1;
    const int l15 = lane & 15, l4 = lane >> 4;

    f32x4 acc[4][4] = {};
    gemm_core(A, Bt, smem, smem + 12288, acc, tid, bm, bn);

    if (z == 2) {
        __syncthreads();
        u16* tl = smem;
#pragma unroll
        for (int n = 0; n < 4; ++n) {
            const int cl = wc * 64 + n * 16 + l15;
            const float bv_ = bias[bn * 128 + cl];
#pragma unroll
            for (int m = 0; m < 4; ++m)
#pragma unroll
                for (int j = 0; j < 4; ++j) {
                    const int rl = wr * 64 + m * 16 + l4 * 4 + j;
                    tl[cl * 132 + rl] = f2bf(acc[m][n][j] + bv_);
                }
        }
        __syncthreads();
        const int bb = bm >> 3, k0 = (bm & 7) * 128;
#pragma unroll
        for (int i = 0; i < 8; ++i) {
            const int idx = i * 256 + tid;
            const int row = idx >> 4, col16 = idx & 15;
            const int cg = bn * 128 + row;
            const int hh = cg >> 6, dd = cg & 63;
            bf16x8 v = *(const bf16x8*)(tl + row * 132 + col16 * 8);
            *(bf16x8*)(VT + ((size_t)((bb * 16 + hh) * 64 + dd)) * 1024 + k0 + col16 * 8) = v;
        }
    } else {
        u16* outp = (z == 0) ? QS : KS;
        const float scale = (z == 0) ? 0.125f : 1.0f;
#pragma unroll
        for (int n = 0; n < 4; ++n) {
            const int c = bn * 128 + wc * 64 + n * 16 + l15;
            const float bv_ = bias[c];
#pragma unroll
            for (int m = 0; m < 4; ++m)
#pragma unroll
                for (int j = 0; j < 4; ++j) {
                    const int r = bm * 128 + wr * 64 + m * 16 + l4 * 4 + j;
                    outp[(size_t)r * 1024 + c] = f2bf((acc[m][n][j] + bv_) * scale);
                }
        }
    }
}

// ---------------- output-projection GEMM (XCD remap) ----------------
__global__ __launch_bounds__(256, 3) void gemm_out(
    const u16* __restrict__ A, const u16* __restrict__ Bt, const float* __restrict__ bias,
    float* __restrict__ outp, const float* __restrict__ resid) {
    __shared__ __align__(16) u16 smem[24576];
    const int tid = threadIdx.x, lane = tid & 63, wid = tid >> 6;
    const int bm = blockIdx.x * 4 + (blockIdx.y >> 3);
    const int bn = blockIdx.y & 7;
    const int wr = wid >> 1, wc = wid & 1;
    const int l15 = lane & 15, l4 = lane >> 4;

    f32x4 acc[4][4] = {};
    gemm_core(A, Bt, smem, smem + 12288, acc, tid, bm, bn);

#pragma unroll
    for (int n = 0; n < 4; ++n) {
        const int c = bn * 128 + wc * 64 + n * 16 + l15;
        const float bv = bias[c];
#pragma unroll
        for (int m = 0; m < 4; ++m)
#pragma unroll
            for (int j = 0; j < 4; ++j) {
                const int r = bm * 128 + wr * 64 + m * 16 + l4 * 4 + j;
                outp[(size_t)r * 1024 + c] = acc[m][n][j] + bv + resid[(size_t)r * 1024 + c];
            }
    }
}

// ---------------- fused geometry attention v9: 2-tile geometry prefetch (512B page bursts) ----------------
// Even body t: stage(t+1) + geom(t+1)->G[(t+1)&3] AND geom(t+2)->G[(t+2)&3] (adjacent 256B
// chunks per row, issued back-to-back -> 512B sequential per row per q-row: DRAM page stays
// open) + mask(t+1). Odd body: stage(t+1) + mask(t+1) only. 4-set static geometry rotation.
// Waits: even bottom vmcnt(12) (16 issued, retire 4 GLL16); odd bottom vmcnt(4) (compiler
// auto-waits for consumed geom/mask retire the rest; retires GLL16(t+2)); t=14 vmcnt(8).
__global__ __launch_bounds__(256, 3) void attn_kernel(
    const u16* __restrict__ Qs, const u16* __restrict__ Ks, const u16* __restrict__ Vt,
    const float* __restrict__ geom, const u64* __restrict__ MBw,
    u16* __restrict__ AO) {
    __shared__ __align__(16) u16 lds[20480];

    const int g = blockIdx.x;
    const int tt = (g & 7) * 128 + (g >> 3);
    const int qb = tt & 15;
    const int bhid = tt >> 4;
    const int b = bhid >> 4, h = bhid & 15;
    const int q0 = qb * 64;

    const int tid = threadIdx.x, lane = tid & 63, wid = tid >> 6;
    const int l15 = lane & 15, l4 = lane >> 4;
    const int qrow = q0 + wid * 16;
    const size_t bh = (size_t)bhid;

    const u16* qp = Qs + (size_t)(b * 1024 + qrow + l15) * 1024 + h * 64 + l4 * 8;
    bf16x8 aq0 = *(const bf16x8*)qp;
    bf16x8 aq1 = *(const bf16x8*)(qp + 32);

    const int r0 = tid >> 3, s0 = tid & 7;
    const int r1 = 32 + r0;
    const int kgr0 = (r0 & 15) * 4 + (r0 >> 4);
    const int kgr1 = (r1 & 15) * 4 + (r1 >> 4);
    const u16* ksrc0 = Ks + (size_t)(b * 1024 + kgr0) * 1024 + h * 64 + ((s0 ^ (r0 & 7)) * 8);
    const u16* ksrc1 = Ks + (size_t)(b * 1024 + kgr1) * 1024 + h * 64 + ((s0 ^ (r1 & 7)) * 8);
    const u16* vsrc0 = Vt + (bh * 64 + r0) * 1024 + ((s0 ^ (r0 & 7)) * 8);
    const u16* vsrc1 = Vt + (bh * 64 + r1) * 1024 + ((s0 ^ (r1 & 7)) * 8);
    u16* const KD = lds + wid * 512;
    u16* const VD = lds + 8192 + wid * 512;
    u16* const pw = lds + 16384 + wid * 1024;

    const float* gbase = geom + (bh * 1024 + qrow + l4 * 4) * 1024 + l15 * 4;
    const u8* mbase8 = (const u8*)MBw + (size_t)(bh * 1024 + qrow + l4 * 4) * 128 + (l15 >> 1);
    const int nsh = (l15 & 1) * 4;

    f32x4 o[4] = {};
    float m_run[4], l_run[4];
#pragma unroll
    for (int j = 0; j < 4; ++j) { m_run[j] = -1e30f; l_run[j] = 0.f; }

    f32x4 G0[4], G1[4], G2[4], G3[4];
    unsigned mkA[4], mkB[4];

    // prologue: stage(0), geom(0)->G0, mask(0)->mkA; vmcnt(8) retires the 4 GLL16.
    GLL16(ksrc0, KD);
    GLL16(ksrc1, KD + 2048);
    GLL16(vsrc0, VD);
    GLL16(vsrc1, VD + 2048);
    __builtin_amdgcn_sched_barrier(0);
#pragma unroll
    for (int j = 0; j < 4; ++j) {
        G0[j] = NTL4(gbase + j * 1024);
        mkA[j] = __builtin_nontemporal_load(mbase8 + j * 128);
    }
    __builtin_amdgcn_sched_barrier(0);
    asm volatile("s_waitcnt vmcnt(8)" ::: "memory");
    __builtin_amdgcn_sched_barrier(0);
    __builtin_amdgcn_s_barrier();
    __builtin_amdgcn_sched_barrier(0);

// compute(t): QK^T + geometry-softmax + PV using geometry set GC, mask MC, LDS bufs of T.
#define ACOMP(T, GC, MC)                                                                 \
    do {                                                                                 \
        const u16* KB = lds + ((T) & 1) * 4096;                                          \
        const u16* VB = lds + 8192 + ((T) & 1) * 4096;                                   \
        f32x4 s[4];                                                                      \
        __builtin_amdgcn_s_setprio(1);                                                   \
        _Pragma("unroll")                                                                \
        for (int nf = 0; nf < 4; ++nf) {                                                 \
            const int rr = nf * 16 + l15, swz = rr & 7;                                  \
            bf16x8 k0 = *(const bf16x8*)(KB + rr * 64 + ((l4 ^ swz) * 8));               \
            bf16x8 k1 = *(const bf16x8*)(KB + rr * 64 + (((4 + l4) ^ swz) * 8));         \
            f32x4 z = {};                                                                \
            z = __builtin_amdgcn_mfma_f32_16x16x32_bf16(aq0, k0, z, 0, 0, 0);            \
            s[nf] = __builtin_amdgcn_mfma_f32_16x16x32_bf16(aq1, k1, z, 0, 0, 0);        \
        }                                                                                \
        __builtin_amdgcn_s_setprio(0);                                                   \
        float sclv[4];                                                                   \
        _Pragma("unroll")                                                                \
        for (int j = 0; j < 4; ++j) {                                                    \
            float mt = fmaxf(fmaxf(s[0][j], s[1][j]), fmaxf(s[2][j], s[3][j]));          \
            mt = fmaxf(mt, __shfl_xor(mt, 1, 16));                                       \
            mt = fmaxf(mt, __shfl_xor(mt, 2, 16));                                       \
            mt = fmaxf(mt, __shfl_xor(mt, 4, 16));                                       \
            mt = fmaxf(mt, __shfl_xor(mt, 8, 16));                                       \
            float mn = fmaxf(m_run[j], mt);                                              \
            float scl = __expf(m_run[j] - mn);                                           \
            m_run[j] = mn;                                                               \
            unsigned nib = (MC[j] >> nsh) & 0xFu;                                        \
            f32x4 gv = GC[j];                                                            \
            float p0 = (nib & 1u) ? 0.f : __expf(s[0][j] - mn) * fmaxf(gv[0], 1e-6f);    \
            float p1 = (nib & 2u) ? 0.f : __expf(s[1][j] - mn) * fmaxf(gv[1], 1e-6f);    \
            float p2 = (nib & 4u) ? 0.f : __expf(s[2][j] - mn) * fmaxf(gv[2], 1e-6f);    \
            float p3 = (nib & 8u) ? 0.f : __expf(s[3][j] - mn) * fmaxf(gv[3], 1e-6f);    \
            float rs = (p0 + p1) + (p2 + p3);                                            \
            rs += __shfl_xor(rs, 1, 16);                                                 \
            rs += __shfl_xor(rs, 2, 16);                                                 \
            rs += __shfl_xor(rs, 4, 16);                                                 \
            rs += __shfl_xor(rs, 8, 16);                                                 \
            l_run[j] = l_run[j] * scl + rs;                                              \
            sclv[j] = scl;                                                               \
            const int row = l4 * 4 + j;                                                  \
            u64 pk = (u64)f2bf(p0) | ((u64)f2bf(p1) << 16) |                             \
                     ((u64)f2bf(p2) << 32) | ((u64)f2bf(p3) << 48);                      \
            *(u64*)(pw + row * 64 + (((l15 >> 1) ^ (row & 7)) * 8) + (l15 & 1) * 4) = pk;\
        }                                                                                \
        _Pragma("unroll")                                                                \
        for (int df = 0; df < 4; ++df) {                                                 \
            f32x4 tv = o[df];                                                            \
            _Pragma("unroll")                                                            \
            for (int j = 0; j < 4; ++j) tv[j] *= sclv[j];                                \
            o[df] = tv;                                                                  \
        }                                                                                \
        {                                                                                \
            const int pswz = l15 & 7;                                                    \
            bf16x8 pa0 = *(const bf16x8*)(pw + l15 * 64 + ((l4 ^ pswz) * 8));            \
            bf16x8 pa1 = *(const bf16x8*)(pw + l15 * 64 + (((4 + l4) ^ pswz) * 8));      \
            __builtin_amdgcn_s_setprio(1);                                               \
            _Pragma("unroll")                                                            \
            for (int df = 0; df < 4; ++df) {                                             \
                const int rr = df * 16 + l15, vswz = rr & 7;                             \
                bf16x8 v0 = *(const bf16x8*)(VB + rr * 64 + ((l4 ^ vswz) * 8));          \
                bf16x8 v1 = *(const bf16x8*)(VB + rr * 64 + (((4 + l4) ^ vswz) * 8));    \
                o[df] = __builtin_amdgcn_mfma_f32_16x16x32_bf16(pa0, v0, o[df], 0, 0, 0);\
                o[df] = __builtin_amdgcn_mfma_f32_16x16x32_bf16(pa1, v1, o[df], 0, 0, 0);\
            }                                                                            \
            __builtin_amdgcn_s_setprio(0);                                               \
        }                                                                                \
    } while (0)

#define ASTG(T)                                                         \
    do {                                                                \
        const int nb = (((T) + 1) & 1) * 4096;                          \
        GLL16(ksrc0 + (size_t)((T) + 1) * 65536, KD + nb);              \
        GLL16(ksrc1 + (size_t)((T) + 1) * 65536, KD + 2048 + nb);       \
        GLL16(vsrc0 + ((T) + 1) * 64, VD + nb);                         \
        GLL16(vsrc1 + ((T) + 1) * 64, VD + 2048 + nb);                  \
    } while (0)

// even body: stage(t+1); geom(t+1)->GN1 and (if LOADG2) geom(t+2)->GN2 back-to-back per row;
// mask(t+1)->MN; compute(t); WSTR; barrier.
#define EBODY(T, GC, GN1, GN2, MC, MN, LOADG2, WSTR)                                     \
    do {                                                                                 \
        ASTG(T);                                                                         \
        __builtin_amdgcn_sched_barrier(0);                                               \
        _Pragma("unroll")                                                                \
        for (int j = 0; j < 4; ++j) {                                                    \
            GN1[j] = NTL4(gbase + j * 1024 + ((T) + 1) * 64);                            \
            if (LOADG2) GN2[j] = NTL4(gbase + j * 1024 + ((T) + 2) * 64);                \
            MN[j] = __builtin_nontemporal_load(mbase8 + j * 128 + ((T) + 1) * 8);        \
        }                                                                                \
        __builtin_amdgcn_sched_barrier(0);                                               \
        ACOMP(T, GC, MC);                                                                \
        asm volatile(WSTR ::: "memory");                                                 \
        __builtin_amdgcn_sched_barrier(0);                                               \
        __builtin_amdgcn_s_barrier();                                                    \
        __builtin_amdgcn_sched_barrier(0);                                               \
    } while (0)

// odd body: stage(t+1) + mask(t+1) (unless LAST); compute(t); vmcnt(4); barrier.
#define OBODY(T, GC, MC, MN, LAST)                                                       \
    do {                                                                                 \
        if (!(LAST)) {                                                                   \
            ASTG(T);                                                                     \
            __builtin_amdgcn_sched_barrier(0);                                           \
            _Pragma("unroll")                                                            \
            for (int j = 0; j < 4; ++j)                                                  \
                MN[j] = __builtin_nontemporal_load(mbase8 + j * 128 + ((T) + 1) * 8);    \
            __builtin_amdgcn_sched_barrier(0);                                           \
        }                                                                                \
        ACOMP(T, GC, MC);                                                                \
        if (!(LAST)) {                                                                   \
            asm volatile("s_waitcnt vmcnt(4)" ::: "memory");                             \
            __builtin_amdgcn_sched_barrier(0);                                           \
            __builtin_amdgcn_s_barrier();                                                \
            __builtin_amdgcn_sched_barrier(0);                                           \
        }                                                                                \
    } while (0)

    for (int it = 0; it < 3; ++it) {
        const int t0 = it * 4;
        EBODY(t0 + 0, G0, G1, G2, mkA, mkB, 1, "s_waitcnt vmcnt(12)");
        OBODY(t0 + 1, G1, mkB, mkA, 0);
        EBODY(t0 + 2, G2, G3, G0, mkA, mkB, 1, "s_waitcnt vmcnt(12)");
        OBODY(t0 + 3, G3, mkB, mkA, 0);
    }
    EBODY(12, G0, G1, G2, mkA, mkB, 1, "s_waitcnt vmcnt(12)");
    OBODY(13, G1, mkB, mkA, 0);
    EBODY(14, G2, G3, G0, mkA, mkB, 0, "s_waitcnt vmcnt(8)");
    OBODY(15, G3, mkB, mkA, 1);
#undef OBODY
#undef EBODY
#undef ASTG
#undef ACOMP

    float inv[4];
#pragma unroll
    for (int j = 0; j < 4; ++j) inv[j] = 1.0f / l_run[j];
#pragma unroll
    for (int df = 0; df < 4; ++df)
#pragma unroll
        for (int j = 0; j < 4; ++j)
            pw[(l4 * 4 + j) * 64 + df * 16 + l15] = f2bf(o[df][j] * inv[j]);
#pragma unroll
    for (int p = 0; p < 2; ++p) {
        const int idx = p * 64 + lane;
        const int er = idx >> 3, ec = idx & 7;
        bf16x8 val = *(const bf16x8*)(pw + er * 64 + ec * 8);
        *(bf16x8*)(AO + (size_t)(b * 1024 + qrow + er) * 1024 + h * 64 + ec * 8) = val;
    }
}

// ---------------- LayerNorm over rows of Y (f32) ----------------
__global__ __launch_bounds__(256) void ln_kernel(const float* __restrict__ Y,
                                                 const float* __restrict__ gamma,
                                                 const float* __restrict__ beta,
                                                 float* __restrict__ out) {
    __shared__ float red[8];
    const int r = blockIdx.x, tid = threadIdx.x, lane = tid & 63, wid = tid >> 6;
    float4 v = ((const float4*)(Y + (size_t)r * 1024))[tid];
    float s = v.x + v.y + v.z + v.w;
    float q = v.x * v.x + v.y * v.y + v.z * v.z + v.w * v.w;
    for (int d = 1; d < 64; d <<= 1) {
        s += __shfl_xor(s, d, 64);
        q += __shfl_xor(q, d, 64);
    }
    if (lane == 0) { red[wid] = s; red[4 + wid] = q; }
    __syncthreads();
    float ts = red[0] + red[1] + red[2] + red[3];
    float tq = red[4] + red[5] + red[6] + red[7];
    float mu = ts * (1.f / 1024.f);
    float var = tq * (1.f / 1024.f) - mu * mu;
    float rstd = rsqrtf(var + 1e-5f);
    float4 gg = ((const float4*)gamma)[tid];
    float4 be = ((const float4*)beta)[tid];
    float4 ov;
    ov.x = (v.x - mu) * rstd * gg.x + be.x;
    ov.y = (v.y - mu) * rstd * gg.y + be.y;
    ov.z = (v.z - mu) * rstd * gg.z + be.z;
    ov.w = (v.w - mu) * rstd * gg.w + be.w;
    ((float4*)(out + (size_t)r * 1024))[tid] = ov;
}

extern "C" void kernel_launch(void* const* d_in, const int* in_sizes, int n_in,
                              void* d_out, int out_size, void* d_ws, size_t ws_size,
                              hipStream_t stream) {
    const float* queries = (const float*)d_in[0];
    const float* keys    = (const float*)d_in[1];
    const float* values  = (const float*)d_in[2];
    const float* geom    = (const float*)d_in[3];
    const void*  mask    = d_in[4];
    const float* Wq = (const float*)d_in[5];  const float* bq = (const float*)d_in[6];
    const float* Wk = (const float*)d_in[7];  const float* bk = (const float*)d_in[8];
    const float* Wv = (const float*)d_in[9];  const float* bv = (const float*)d_in[10];
    const float* Wo = (const float*)d_in[11]; const float* bo = (const float*)d_in[12];
    const float* gamma = (const float*)d_in[13];
    const float* beta  = (const float*)d_in[14];

    char* ws = (char*)d_ws;
    const size_t MB_ = 1024 * 1024;
    u16* XQ  = (u16*)(ws + 0);
    u16* XK  = (u16*)(ws + 8 * MB_);
    u16* XV  = (u16*)(ws + 16 * MB_);
    u16* WQT = (u16*)(ws + 24 * MB_);
    u16* WKT = (u16*)(ws + 26 * MB_);
    u16* WVT = (u16*)(ws + 28 * MB_);
    u16* WOT = (u16*)(ws + 30 * MB_);
    u16* QS  = (u16*)(ws + 32 * MB_);
    u16* KS  = (u16*)(ws + 40 * MB_);
    u16* VT  = (u16*)(ws + 48 * MB_);
    u16* AO  = (u16*)(ws + 56 * MB_);
    u64* MBITS = (u64*)(ws + 64 * MB_);
    float* Y = (float*)(ws + 0);

    prep_kernel<<<2048, 256, 0, stream>>>(queries, keys, values, XQ, XK, XV,
                                          Wq, Wk, Wv, Wo, WQT, WKT, WVT, WOT);
    qkv_gemm<<<dim3(8, 32, 4), 256, 0, stream>>>(XQ, XK, XV, WQT, WKT, WVT, bq, bk, bv,
                                                 QS, KS, VT, mask, MBITS);
    attn_kernel<<<1024, 256, 0, stream>>>(QS, KS, VT, geom, MBITS, AO);
    gemm_out<<<dim3(8, 32), 256, 0, stream>>>(AO, WOT, bo, Y, queries);
    ln_kernel<<<4096, 256, 0, stream>>>(Y, gamma, beta, (float*)d_out);
}

// Round 18
// 260.377 us; speedup vs baseline: 1.0662x; 1.0662x over previous
//
#include <hip/hip_runtime.h>
#include <hip/hip_bf16.h>

typedef unsigned short u16;
typedef unsigned char u8;
typedef unsigned long long u64;
typedef __bf16 bf16x8 __attribute__((ext_vector_type(8)));
typedef float f32x4 __attribute__((ext_vector_type(4)));

#define AS1 __attribute__((address_space(1)))
#define AS3 __attribute__((address_space(3)))
#define GLL16(gp, lp) __builtin_amdgcn_global_load_lds((AS1 const unsigned int*)(gp), (AS3 unsigned int*)(lp), 16, 0, 0)
#define NTL4(p) __builtin_nontemporal_load((const f32x4*)(p))

__device__ __forceinline__ u16 f2bf(float f) {
    unsigned u = __builtin_bit_cast(unsigned, f);
    unsigned r = u + 0x7FFFu + ((u >> 16) & 1u);
    return (u16)(r >> 16);
}

// ---------------- prep: f32->bf16 cast of Q/K/V (blocks 0..1023) + weight transpose (1024..2047) ----------------
__global__ __launch_bounds__(256) void prep_kernel(
    const float* __restrict__ q, const float* __restrict__ k, const float* __restrict__ v,
    u16* __restrict__ xq, u16* __restrict__ xk, u16* __restrict__ xv,
    const float* __restrict__ W0, const float* __restrict__ W1,
    const float* __restrict__ W2, const float* __restrict__ W3,
    u16* __restrict__ T0, u16* __restrict__ T1, u16* __restrict__ T2, u16* __restrict__ T3) {
    const int gb = blockIdx.x, tid = threadIdx.x;
    if (gb < 1024) {
        const int n4 = 4 * 1024 * 1024 / 4;
        const int stride = 1024 * 256;
        for (int i = gb * 256 + tid; i < n4; i += stride) {
            float4 a = ((const float4*)q)[i];
            float4 b = ((const float4*)k)[i];
            float4 c = ((const float4*)v)[i];
            ((ushort4*)xq)[i] = make_ushort4(f2bf(a.x), f2bf(a.y), f2bf(a.z), f2bf(a.w));
            ((ushort4*)xk)[i] = make_ushort4(f2bf(b.x), f2bf(b.y), f2bf(b.z), f2bf(b.w));
            ((ushort4*)xv)[i] = make_ushort4(f2bf(c.x), f2bf(c.y), f2bf(c.z), f2bf(c.w));
        }
    } else {
        __shared__ float t[64][65];
        const int idx = gb - 1024;
        const int bz = idx >> 8, by = (idx >> 4) & 15, bx = idx & 15;
        const float* W = (bz == 0) ? W0 : (bz == 1) ? W1 : (bz == 2) ? W2 : W3;
        u16* T = (bz == 0) ? T0 : (bz == 1) ? T1 : (bz == 2) ? T2 : T3;
        const int n0 = bx * 64, k0 = by * 64;
        const int tx = tid & 63, ty = tid >> 6;
        for (int j = ty; j < 64; j += 4) t[j][tx] = W[(size_t)(k0 + j) * 1024 + n0 + tx];
        __syncthreads();
        for (int j = ty; j < 64; j += 4) T[(size_t)(n0 + j) * 1024 + k0 + tx] = f2bf(t[tx][j]);
    }
}

// ---------------- mask -> packed bitmask body (self-detecting dtype); runs as qkv z==3 ----------------
#define MN_LOOP(PRED)                                                     \
    for (int row = wave; row < 65536; row += nw) {                        \
        size_t base = (size_t)row * 1024;                                 \
        u64 myw = 0;                                                      \
        _Pragma("unroll")                                                 \
        for (int kb = 0; kb < 16; ++kb) {                                 \
            size_t gi = base + kb * 64 + lane;                            \
            bool p = (PRED);                                              \
            u64 w = __ballot(p);                                          \
            if (lane == kb) myw = w;                                      \
        }                                                                 \
        if (lane < 16) MB[(size_t)row * 16 + lane] = myw;                 \
    }

__device__ __forceinline__ void masknorm_body(const void* __restrict__ mp,
                                              u64* __restrict__ MB,
                                              int* sh, int tid, int wave, int nw) {
    if (tid == 0) { sh[0] = 0; sh[1] = 0; }
    __syncthreads();
    {
        const u8* m8 = (const u8*)mp;
        int c1 = 0, bg = 0;
        for (int i = tid; i < 16384; i += 256) {
            u8 vv = m8[i];
            if (vv) {
                if ((i & 3) == 1) c1++;
                if (vv > 1) bg++;
            }
        }
        atomicAdd(&sh[0], c1);
        atomicAdd(&sh[1], bg);
    }
    __syncthreads();
    const int flag = (sh[1] == 0) ? (sh[0] ? 0 : 1) : (sh[0] ? 3 : 2);
    const int lane = tid & 63;
    if (flag == 0) {
        const u8* m8 = (const u8*)mp;
        MN_LOOP(m8[gi] != 0)
    } else if (flag == 1) {
        const int* m32 = (const int*)mp;
        MN_LOOP(m32[gi] != 0)
    } else if (flag == 2) {
        const unsigned* mf = (const unsigned*)mp;
        MN_LOOP((mf[gi] << 1) != 0)
    } else {
        const u16* mb = (const u16*)mp;
        MN_LOOP((mb[gi] & 0x7FFF) != 0)
    }
}

// ================= GEMM core v2 (round 10, unchanged) =================
__device__ __forceinline__ void gemm_core(const u16* __restrict__ A, const u16* __restrict__ Bt,
                                          u16* sA, u16* sB, f32x4 (&acc)[4][4],
                                          int tid, int bm, int bn) {
    const int lane = tid & 63, wid = tid >> 6;
    const int wr = wid >> 1, wc = wid & 1;
    const int l15 = lane & 15, l4 = lane >> 4;
    const int srow = tid >> 2, sslot = tid & 3;
    const int soff = (sslot ^ ((srow >> 1) & 3)) * 8;
    const u16* aSrc = A + (size_t)(bm * 128 + srow) * 1024 + soff;
    const u16* bSrc = Bt + (size_t)(bn * 128 + srow) * 1024 + soff;
    u16* const dA0 = sA + wid * 512;
    u16* const dA1 = sA + 2048 + wid * 512;
    u16* const dB0 = sB + wid * 512;
    u16* const dB1 = sB + 2048 + wid * 512;

#define GSTAGE(BUF, T)                                                  \
    do {                                                                \
        GLL16(aSrc + (T) * 32, dA0 + (BUF) * 4096);                     \
        GLL16(aSrc + 65536 + (T) * 32, dA1 + (BUF) * 4096);             \
        GLL16(bSrc + (T) * 32, dB0 + (BUF) * 4096);                     \
        GLL16(bSrc + 65536 + (T) * 32, dB1 + (BUF) * 4096);             \
    } while (0)

#define GCOMPUTE(BUF)                                                             \
    do {                                                                          \
        bf16x8 af[4], bfv[4];                                                     \
        _Pragma("unroll")                                                         \
        for (int m = 0; m < 4; ++m) {                                             \
            const int rr = wr * 64 + m * 16 + l15;                                \
            af[m] = *(const bf16x8*)(sA + (BUF) * 4096 + rr * 32 +                \
                                     ((l4 ^ ((rr >> 1) & 3)) * 8));               \
        }                                                                         \
        _Pragma("unroll")                                                         \
        for (int n = 0; n < 4; ++n) {                                             \
            const int rr = wc * 64 + n * 16 + l15;                                \
            bfv[n] = *(const bf16x8*)(sB + (BUF) * 4096 + rr * 32 +               \
                                      ((l4 ^ ((rr >> 1) & 3)) * 8));              \
        }                                                                         \
        _Pragma("unroll")                                                         \
        for (int m = 0; m < 4; ++m)                                               \
            _Pragma("unroll")                                                     \
            for (int n = 0; n < 4; ++n)                                           \
                acc[m][n] = __builtin_amdgcn_mfma_f32_16x16x32_bf16(af[m], bfv[n], acc[m][n], 0, 0, 0); \
    } while (0)

#define GBODY(T, BUF, NBUF, WSTR)                                       \
    do {                                                                \
        if ((T) + 2 < 32) {                                             \
            GSTAGE(NBUF, (T) + 2);                                      \
            __builtin_amdgcn_sched_barrier(0);                          \
        }                                                               \
        GCOMPUTE(BUF);                                                  \
        if ((T) + 1 < 32) {                                             \
            asm volatile(WSTR ::: "memory");                            \
            __builtin_amdgcn_sched_barrier(0);                          \
            __builtin_amdgcn_s_barrier();                               \
            __builtin_amdgcn_sched_barrier(0);                          \
        }                                                               \
    } while (0)

    GSTAGE(0, 0);
    GSTAGE(1, 1);
    __builtin_amdgcn_sched_barrier(0);
    asm volatile("s_waitcnt vmcnt(4)" ::: "memory");
    __builtin_amdgcn_sched_barrier(0);
    __builtin_amdgcn_s_barrier();
    __builtin_amdgcn_sched_barrier(0);

    for (int it = 0; it < 10; ++it) {
        const int t0 = it * 3;
        GBODY(t0 + 0, 0, 2, "s_waitcnt vmcnt(4)");
        GBODY(t0 + 1, 1, 0, "s_waitcnt vmcnt(4)");
        GBODY(t0 + 2, 2, 1, "s_waitcnt vmcnt(4)");
    }
    GBODY(30, 0, 2, "s_waitcnt vmcnt(0)");
    GBODY(31, 1, 0, "s_waitcnt vmcnt(0)");
#undef GBODY
#undef GCOMPUTE
#undef GSTAGE
}

// ---------------- merged QKV GEMM + masknorm (z==3): XCD-locality remap ----------------
__global__ __launch_bounds__(256, 3) void qkv_gemm(
    const u16* __restrict__ XQ, const u16* __restrict__ XK, const u16* __restrict__ XV,
    const u16* __restrict__ WQT, const u16* __restrict__ WKT, const u16* __restrict__ WVT,
    const float* __restrict__ bq, const float* __restrict__ bk, const float* __restrict__ bv,
    u16* __restrict__ QS, u16* __restrict__ KS, u16* __restrict__ VT,
    const void* __restrict__ maskp, u64* __restrict__ MBw) {
    __shared__ __align__(16) u16 smem[24576];
    const int z = blockIdx.z;
    const int tid = threadIdx.x;
    if (z == 3) {
        const int wave = (blockIdx.y * 8 + blockIdx.x) * 4 + (tid >> 6);
        masknorm_body(maskp, MBw, (int*)smem, tid, wave, 1024);
        return;
    }
    const u16* A  = (z == 0) ? XQ : (z == 1) ? XK : XV;
    const u16* Bt = (z == 0) ? WQT : (z == 1) ? WKT : WVT;
    const float* bias = (z == 0) ? bq : (z == 1) ? bk : bv;
    const int lane = tid & 63, wid = tid >> 6;
    const int bm = blockIdx.x * 4 + (blockIdx.y >> 3);
    const int bn = blockIdx.y & 7;
    const int wr = wid >> 1, wc = wid & 1;
    const int l15 = lane & 15, l4 = lane >> 4;

    f32x4 acc[4][4] = {};
    gemm_core(A, Bt, smem, smem + 12288, acc, tid, bm, bn);

    if (z == 2) {
        __syncthreads();
        u16* tl = smem;
#pragma unroll
        for (int n = 0; n < 4; ++n) {
            const int cl = wc * 64 + n * 16 + l15;
            const float bv_ = bias[bn * 128 + cl];
#pragma unroll
            for (int m = 0; m < 4; ++m)
#pragma unroll
                for (int j = 0; j < 4; ++j) {
                    const int rl = wr * 64 + m * 16 + l4 * 4 + j;
                    tl[cl * 132 + rl] = f2bf(acc[m][n][j] + bv_);
                }
        }
        __syncthreads();
        const int bb = bm >> 3, k0 = (bm & 7) * 128;
#pragma unroll
        for (int i = 0; i < 8; ++i) {
            const int idx = i * 256 + tid;
            const int row = idx >> 4, col16 = idx & 15;
            const int cg = bn * 128 + row;
            const int hh = cg >> 6, dd = cg & 63;
            bf16x8 v = *(const bf16x8*)(tl + row * 132 + col16 * 8);
            *(bf16x8*)(VT + ((size_t)((bb * 16 + hh) * 64 + dd)) * 1024 + k0 + col16 * 8) = v;
        }
    } else {
        u16* outp = (z == 0) ? QS : KS;
        const float scale = (z == 0) ? 0.125f : 1.0f;
#pragma unroll
        for (int n = 0; n < 4; ++n) {
            const int c = bn * 128 + wc * 64 + n * 16 + l15;
            const float bv_ = bias[c];
#pragma unroll
            for (int m = 0; m < 4; ++m)
#pragma unroll
                for (int j = 0; j < 4; ++j) {
                    const int r = bm * 128 + wr * 64 + m * 16 + l4 * 4 + j;
                    outp[(size_t)r * 1024 + c] = f2bf((acc[m][n][j] + bv_) * scale);
                }
        }
    }
}

// ---------------- output-projection GEMM (XCD remap) ----------------
__global__ __launch_bounds__(256, 3) void gemm_out(
    const u16* __restrict__ A, const u16* __restrict__ Bt, const float* __restrict__ bias,
    float* __restrict__ outp, const float* __restrict__ resid) {
    __shared__ __align__(16) u16 smem[24576];
    const int tid = threadIdx.x, lane = tid & 63, wid = tid >> 6;
    const int bm = blockIdx.x * 4 + (blockIdx.y >> 3);
    const int bn = blockIdx.y & 7;
    const int wr = wid >> 1, wc = wid & 1;
    const int l15 = lane & 15, l4 = lane >> 4;

    f32x4 acc[4][4] = {};
    gemm_core(A, Bt, smem, smem + 12288, acc, tid, bm, bn);

#pragma unroll
    for (int n = 0; n < 4; ++n) {
        const int c = bn * 128 + wc * 64 + n * 16 + l15;
        const float bv = bias[c];
#pragma unroll
        for (int m = 0; m < 4; ++m)
#pragma unroll
            for (int j = 0; j < 4; ++j) {
                const int r = bm * 128 + wr * 64 + m * 16 + l4 * 4 + j;
                outp[(size_t)r * 1024 + c] = acc[m][n][j] + bv + resid[(size_t)r * 1024 + c];
            }
    }
}

// ---------------- fused geometry attention v8c (round 16 best config, reverted) ----------------
__global__ __launch_bounds__(256, 3) void attn_kernel(
    const u16* __restrict__ Qs, const u16* __restrict__ Ks, const u16* __restrict__ Vt,
    const float* __restrict__ geom, const u64* __restrict__ MBw,
    u16* __restrict__ AO) {
    __shared__ __align__(16) u16 lds[20480];

    const int g = blockIdx.x;
    const int tt = (g & 7) * 128 + (g >> 3);
    const int qb = tt & 15;
    const int bhid = tt >> 4;
    const int b = bhid >> 4, h = bhid & 15;
    const int q0 = qb * 64;

    const int tid = threadIdx.x, lane = tid & 63, wid = tid >> 6;
    const int l15 = lane & 15, l4 = lane >> 4;
    const int qrow = q0 + wid * 16;
    const size_t bh = (size_t)bhid;

    const u16* qp = Qs + (size_t)(b * 1024 + qrow + l15) * 1024 + h * 64 + l4 * 8;
    bf16x8 aq0 = *(const bf16x8*)qp;
    bf16x8 aq1 = *(const bf16x8*)(qp + 32);

    const int r0 = tid >> 3, s0 = tid & 7;
    const int r1 = 32 + r0;
    const int kgr0 = (r0 & 15) * 4 + (r0 >> 4);
    const int kgr1 = (r1 & 15) * 4 + (r1 >> 4);
    const u16* ksrc0 = Ks + (size_t)(b * 1024 + kgr0) * 1024 + h * 64 + ((s0 ^ (r0 & 7)) * 8);
    const u16* ksrc1 = Ks + (size_t)(b * 1024 + kgr1) * 1024 + h * 64 + ((s0 ^ (r1 & 7)) * 8);
    const u16* vsrc0 = Vt + (bh * 64 + r0) * 1024 + ((s0 ^ (r0 & 7)) * 8);
    const u16* vsrc1 = Vt + (bh * 64 + r1) * 1024 + ((s0 ^ (r1 & 7)) * 8);
    u16* const KD = lds + wid * 512;
    u16* const VD = lds + 8192 + wid * 512;
    u16* const pw = lds + 16384 + wid * 1024;

    const float* gbase = geom + (bh * 1024 + qrow + l4 * 4) * 1024 + l15 * 4;
    const u8* mbase8 = (const u8*)MBw + (size_t)(bh * 1024 + qrow + l4 * 4) * 128 + (l15 >> 1);
    const int nsh = (l15 & 1) * 4;

    f32x4 o[4] = {};
    float m_run[4], l_run[4];
#pragma unroll
    for (int j = 0; j < 4; ++j) { m_run[j] = -1e30f; l_run[j] = 0.f; }

    f32x4 gpA[4], gpB[4];
    unsigned mkA[4], mkB[4];

    GLL16(ksrc0, KD);
    GLL16(ksrc1, KD + 2048);
    GLL16(vsrc0, VD);
    GLL16(vsrc1, VD + 2048);
    __builtin_amdgcn_sched_barrier(0);
#pragma unroll
    for (int j = 0; j < 4; ++j) {
        gpA[j] = NTL4(gbase + j * 1024);
        mkA[j] = __builtin_nontemporal_load(mbase8 + j * 128);
    }
    __builtin_amdgcn_sched_barrier(0);
    asm volatile("s_waitcnt vmcnt(8)" ::: "memory");
    __builtin_amdgcn_sched_barrier(0);
    __builtin_amdgcn_s_barrier();
    __builtin_amdgcn_sched_barrier(0);

#define BODY(T, G, GC, GN, MC, MN)                                                       \
    do {                                                                                 \
        const u16* KB = lds + ((T) & 1) * 4096;                                          \
        const u16* VB = lds + 8192 + ((T) & 1) * 4096;                                   \
        if (G) {                                                                         \
            const int nb = (((T) + 1) & 1) * 4096;                                       \
            GLL16(ksrc0 + (size_t)((T) + 1) * 65536, KD + nb);                           \
            GLL16(ksrc1 + (size_t)((T) + 1) * 65536, KD + 2048 + nb);                    \
            GLL16(vsrc0 + ((T) + 1) * 64, VD + nb);                                      \
            GLL16(vsrc1 + ((T) + 1) * 64, VD + 2048 + nb);                               \
            __builtin_amdgcn_sched_barrier(0);                                           \
            _Pragma("unroll")                                                            \
            for (int j = 0; j < 4; ++j) {                                                \
                GN[j] = NTL4(gbase + j * 1024 + ((T) + 1) * 64);                         \
                MN[j] = __builtin_nontemporal_load(mbase8 + j * 128 + ((T) + 1) * 8);    \
            }                                                                            \
            __builtin_amdgcn_sched_barrier(0);                                           \
        }                                                                                \
        f32x4 s[4];                                                                      \
        __builtin_amdgcn_s_setprio(1);                                                   \
        _Pragma("unroll")                                                                \
        for (int nf = 0; nf < 4; ++nf) {                                                 \
            const int rr = nf * 16 + l15, swz = rr & 7;                                  \
            bf16x8 k0 = *(const bf16x8*)(KB + rr * 64 + ((l4 ^ swz) * 8));               \
            bf16x8 k1 = *(const bf16x8*)(KB + rr * 64 + (((4 + l4) ^ swz) * 8));         \
            f32x4 z = {};                                                                \
            z = __builtin_amdgcn_mfma_f32_16x16x32_bf16(aq0, k0, z, 0, 0, 0);            \
            s[nf] = __builtin_amdgcn_mfma_f32_16x16x32_bf16(aq1, k1, z, 0, 0, 0);        \
        }                                                                                \
        __builtin_amdgcn_s_setprio(0);                                                   \
        float sclv[4];                                                                   \
        _Pragma("unroll")                                                                \
        for (int j = 0; j < 4; ++j) {                                                    \
            float mt = fmaxf(fmaxf(s[0][j], s[1][j]), fmaxf(s[2][j], s[3][j]));          \
            mt = fmaxf(mt, __shfl_xor(mt, 1, 16));                                       \
            mt = fmaxf(mt, __shfl_xor(mt, 2, 16));                                       \
            mt = fmaxf(mt, __shfl_xor(mt, 4, 16));                                       \
            mt = fmaxf(mt, __shfl_xor(mt, 8, 16));                                       \
            float mn = fmaxf(m_run[j], mt);                                              \
            float scl = __expf(m_run[j] - mn);                                           \
            m_run[j] = mn;                                                               \
            unsigned nib = (MC[j] >> nsh) & 0xFu;                                        \
            f32x4 gv = GC[j];                                                            \
            float p0 = (nib & 1u) ? 0.f : __expf(s[0][j] - mn) * fmaxf(gv[0], 1e-6f);    \
            float p1 = (nib & 2u) ? 0.f : __expf(s[1][j] - mn) * fmaxf(gv[1], 1e-6f);    \
            float p2 = (nib & 4u) ? 0.f : __expf(s[2][j] - mn) * fmaxf(gv[2], 1e-6f);    \
            float p3 = (nib & 8u) ? 0.f : __expf(s[3][j] - mn) * fmaxf(gv[3], 1e-6f);    \
            float rs = (p0 + p1) + (p2 + p3);                                            \
            rs += __shfl_xor(rs, 1, 16);                                                 \
            rs += __shfl_xor(rs, 2, 16);                                                 \
            rs += __shfl_xor(rs, 4, 16);                                                 \
            rs += __shfl_xor(rs, 8, 16);                                                 \
            l_run[j] = l_run[j] * scl + rs;                                              \
            sclv[j] = scl;                                                               \
            const int row = l4 * 4 + j;                                                  \
            u64 pk = (u64)f2bf(p0) | ((u64)f2bf(p1) << 16) |                             \
                     ((u64)f2bf(p2) << 32) | ((u64)f2bf(p3) << 48);                      \
            *(u64*)(pw + row * 64 + (((l15 >> 1) ^ (row & 7)) * 8) + (l15 & 1) * 4) = pk;\
        }                                                                                \
        _Pragma("unroll")                                                                \
        for (int df = 0; df < 4; ++df) {                                                 \
            f32x4 tv = o[df];                                                            \
            _Pragma("unroll")                                                            \
            for (int j = 0; j < 4; ++j) tv[j] *= sclv[j];                                \
            o[df] = tv;                                                                  \
        }                                                                                \
        {                                                                                \
            const int pswz = l15 & 7;                                                    \
            bf16x8 pa0 = *(const bf16x8*)(pw + l15 * 64 + ((l4 ^ pswz) * 8));            \
            bf16x8 pa1 = *(const bf16x8*)(pw + l15 * 64 + (((4 + l4) ^ pswz) * 8));      \
            __builtin_amdgcn_s_setprio(1);                                               \
            _Pragma("unroll")                                                            \
            for (int df = 0; df < 4; ++df) {                                             \
                const int rr = df * 16 + l15, vswz = rr & 7;                             \
                bf16x8 v0 = *(const bf16x8*)(VB + rr * 64 + ((l4 ^ vswz) * 8));          \
                bf16x8 v1 = *(const bf16x8*)(VB + rr * 64 + (((4 + l4) ^ vswz) * 8));    \
                o[df] = __builtin_amdgcn_mfma_f32_16x16x32_bf16(pa0, v0, o[df], 0, 0, 0);\
                o[df] = __builtin_amdgcn_mfma_f32_16x16x32_bf16(pa1, v1, o[df], 0, 0, 0);\
            }                                                                            \
            __builtin_amdgcn_s_setprio(0);                                               \
        }                                                                                \
        if (G) {                                                                         \
            asm volatile("s_waitcnt vmcnt(8)" ::: "memory");                             \
            __builtin_amdgcn_sched_barrier(0);                                           \
            __builtin_amdgcn_s_barrier();                                                \
            __builtin_amdgcn_sched_barrier(0);                                           \
        }                                                                                \
    } while (0)

    for (int it = 0; it < 7; ++it) {
        const int t0 = it * 2;
        BODY(t0,     1, gpA, gpB, mkA, mkB);
        BODY(t0 + 1, 1, gpB, gpA, mkB, mkA);
    }
    BODY(14, 1, gpA, gpB, mkA, mkB);
    BODY(15, 0, gpB, gpA, mkB, mkA);
#undef BODY

    float inv[4];
#pragma unroll
    for (int j = 0; j < 4; ++j) inv[j] = 1.0f / l_run[j];
#pragma unroll
    for (int df = 0; df < 4; ++df)
#pragma unroll
        for (int j = 0; j < 4; ++j)
            pw[(l4 * 4 + j) * 64 + df * 16 + l15] = f2bf(o[df][j] * inv[j]);
#pragma unroll
    for (int p = 0; p < 2; ++p) {
        const int idx = p * 64 + lane;
        const int er = idx >> 3, ec = idx & 7;
        bf16x8 val = *(const bf16x8*)(pw + er * 64 + ec * 8);
        *(bf16x8*)(AO + (size_t)(b * 1024 + qrow + er) * 1024 + h * 64 + ec * 8) = val;
    }
}

// ---------------- LayerNorm over rows of Y (f32), XCD-affine to gemm_out's Y tiles ----------------
// gemm_out XCD x produces Y rows [512x, 512x+512) (2 MB, L2-resident). ln block i -> XCD
// (i % 8) by dispatch round-robin; remap row = (i&7)*512 + (i>>3) so each block reads Y
// rows from its own XCD's L2 (bijective over 4096).
__global__ __launch_bounds__(256) void ln_kernel(const float* __restrict__ Y,
                                                 const float* __restrict__ gamma,
                                                 const float* __restrict__ beta,
                                                 float* __restrict__ out) {
    __shared__ float red[8];
    const int bid = blockIdx.x;
    const int r = (bid & 7) * 512 + (bid >> 3);
    const int tid = threadIdx.x, lane = tid & 63, wid = tid >> 6;
    float4 v = ((const float4*)(Y + (size_t)r * 1024))[tid];
    float s = v.x + v.y + v.z + v.w;
    float q = v.x * v.x + v.y * v.y + v.z * v.z + v.w * v.w;
    for (int d = 1; d < 64; d <<= 1) {
        s += __shfl_xor(s, d, 64);
        q += __shfl_xor(q, d, 64);
    }
    if (lane == 0) { red[wid] = s; red[4 + wid] = q; }
    __syncthreads();
    float ts = red[0] + red[1] + red[2] + red[3];
    float tq = red[4] + red[5] + red[6] + red[7];
    float mu = ts * (1.f / 1024.f);
    float var = tq * (1.f / 1024.f) - mu * mu;
    float rstd = rsqrtf(var + 1e-5f);
    float4 gg = ((const float4*)gamma)[tid];
    float4 be = ((const float4*)beta)[tid];
    float4 ov;
    ov.x = (v.x - mu) * rstd * gg.x + be.x;
    ov.y = (v.y - mu) * rstd * gg.y + be.y;
    ov.z = (v.z - mu) * rstd * gg.z + be.z;
    ov.w = (v.w - mu) * rstd * gg.w + be.w;
    ((float4*)(out + (size_t)r * 1024))[tid] = ov;
}

extern "C" void kernel_launch(void* const* d_in, const int* in_sizes, int n_in,
                              void* d_out, int out_size, void* d_ws, size_t ws_size,
                              hipStream_t stream) {
    const float* queries = (const float*)d_in[0];
    const float* keys    = (const float*)d_in[1];
    const float* values  = (const float*)d_in[2];
    const float* geom    = (const float*)d_in[3];
    const void*  mask    = d_in[4];
    const float* Wq = (const float*)d_in[5];  const float* bq = (const float*)d_in[6];
    const float* Wk = (const float*)d_in[7];  const float* bk = (const float*)d_in[8];
    const float* Wv = (const float*)d_in[9];  const float* bv = (const float*)d_in[10];
    const float* Wo = (const float*)d_in[11]; const float* bo = (const float*)d_in[12];
    const float* gamma = (const float*)d_in[13];
    const float* beta  = (const float*)d_in[14];

    char* ws = (char*)d_ws;
    const size_t MB_ = 1024 * 1024;
    u16* XQ  = (u16*)(ws + 0);
    u16* XK  = (u16*)(ws + 8 * MB_);
    u16* XV  = (u16*)(ws + 16 * MB_);
    u16* WQT = (u16*)(ws + 24 * MB_);
    u16* WKT = (u16*)(ws + 26 * MB_);
    u16* WVT = (u16*)(ws + 28 * MB_);
    u16* WOT = (u16*)(ws + 30 * MB_);
    u16* QS  = (u16*)(ws + 32 * MB_);
    u16* KS  = (u16*)(ws + 40 * MB_);
    u16* VT  = (u16*)(ws + 48 * MB_);
    u16* AO  = (u16*)(ws + 56 * MB_);
    u64* MBITS = (u64*)(ws + 64 * MB_);
    float* Y = (float*)(ws + 0);

    prep_kernel<<<2048, 256, 0, stream>>>(queries, keys, values, XQ, XK, XV,
                                          Wq, Wk, Wv, Wo, WQT, WKT, WVT, WOT);
    qkv_gemm<<<dim3(8, 32, 4), 256, 0, stream>>>(XQ, XK, XV, WQT, WKT, WVT, bq, bk, bv,
                                                 QS, KS, VT, mask, MBITS);
    attn_kernel<<<1024, 256, 0, stream>>>(QS, KS, VT, geom, MBITS, AO);
    gemm_out<<<dim3(8, 32), 256, 0, stream>>>(AO, WOT, bo, Y, queries);
    ln_kernel<<<4096, 256, 0, stream>>>(Y, gamma, beta, (float*)d_out);
}